// Round 10
// baseline (216.365 us; speedup 1.0000x reference)
//
#include <hip/hip_runtime.h>
#include <math.h>

#define ALPHA 0.2f

// Padded strides: odd multiples of 64B lines to kill L1 set-aliasing
#define XS   544    // xbf / hamT row stride in shorts (17 lines)
#define HS   4128   // hBT col stride in shorts (129 lines)
#define HCS  66048  // 16 cols * HS

typedef __attribute__((ext_vector_type(8))) short short8;
typedef __attribute__((ext_vector_type(4))) float f32x4;
typedef __attribute__((ext_vector_type(4))) int i32x4;

__device__ __forceinline__ unsigned short f2bf(float f) {
    unsigned int x = __float_as_uint(f);
    x += 0x7fffu + ((x >> 16) & 1u);   // RNE
    return (unsigned short)(x >> 16);
}
__device__ __forceinline__ unsigned int pack_rne(float lo, float hi) {
    return (unsigned int)f2bf(lo) | ((unsigned int)f2bf(hi) << 16);
}
// truncating bf16 pack (bias cancels in w/L since L sums the same truncated w)
__device__ __forceinline__ unsigned int pack_trunc(float lo, float hi) {
    return __builtin_amdgcn_perm(__float_as_uint(hi), __float_as_uint(lo), 0x07060302u);
}
// bit j of x -> 0x0 / 0xFFFFFFFF
__device__ __forceinline__ unsigned int bitmask1(unsigned int x, int j) {
    return (unsigned int)(((int)(x << (31 - j))) >> 31);
}

// ---------------------------------------------------------------------------
// K0 (fused prep): [0,1024): x fp32->bf16 (padded rows). [1024,1152):
// hamilton transposed bf16. [1152,3200): adj -> 1-bit mask, TRANSPOSED
// layout adjpT[m-chunk(128)][row(4096)] (uint32 = 32 m-bits) so k_attn's
// per-stage mask load is one 64B line per wave. Writes coalesced (gid=index).
// ---------------------------------------------------------------------------
__global__ __launch_bounds__(256) void k_prep(const float* __restrict__ x,
                                              const float* __restrict__ W,
                                              const int* __restrict__ adj,
                                              unsigned short* __restrict__ xbf,
                                              unsigned short* __restrict__ hamT,
                                              unsigned int* __restrict__ adjpT) {
    const int b = blockIdx.x;
    if (b < 1024) {                       // ---- x convert: 2M elems, 8/thread
        const int gid = b * 256 + threadIdx.x;
        const int row = gid >> 6, c8 = (gid & 63) * 8;
        const float4* xp = (const float4*)x + (size_t)gid * 2;
        const float4 f0 = xp[0], f1 = xp[1];
        const uint4 o = {pack_rne(f0.x, f0.y), pack_rne(f0.z, f0.w),
                         pack_rne(f1.x, f1.y), pack_rne(f1.z, f1.w)};
        *(uint4*)(xbf + (size_t)row * XS + c8) = o;
    } else if (b < 1152) {                // ---- hamilton: sign mask 0x5390
        const int gid = (b - 1024) * 256 + threadIdx.x;    // 32768
        const int head = gid >> 13;
        const int rem  = gid & 8191;
        const int o = rem >> 6, f8 = rem & 63;
        const int ob = o >> 5, oc = o & 31;
        float v[8];
#pragma unroll
        for (int j = 0; j < 8; j++) {
            const int f = f8 * 8 + j;
            const int bq = f >> 7, f0 = f & 127;
            const float s = ((0x5390u >> ((bq << 2) | ob)) & 1u) ? -1.0f : 1.0f;
            v[j] = s * W[(head << 14) + (f0 << 7) + (((bq ^ ob) << 5) | oc)];
        }
        const uint4 pk = {pack_rne(v[0], v[1]), pack_rne(v[2], v[3]),
                          pack_rne(v[4], v[5]), pack_rne(v[6], v[7])};
        *(uint4*)(hamT + (size_t)(head * 128 + o) * XS + f8 * 8) = pk;
    } else {                              // ---- adj bit-pack (transposed out)
        const int gid = (b - 1152) * 256 + threadIdx.x;    // 0..524287
        const int mcch = gid >> 12;        // m-chunk 0..127
        const int row  = gid & 4095;
        const int4* ap = (const int4*)(adj + (size_t)row * 4096 + mcch * 32);
        unsigned int u = 0;
#pragma unroll
        for (int q = 0; q < 8; q++) {
            const int4 v = ap[q];
            u |= (v.x > 0 ? 1u : 0u) << (q * 4);
            u |= (v.y > 0 ? 2u : 0u) << (q * 4);
            u |= (v.z > 0 ? 4u : 0u) << (q * 4);
            u |= (v.w > 0 ? 8u : 0u) << (q * 4);
        }
        adjpT[gid] = u;                    // [mcch][row], coalesced
    }
}

// ---------------------------------------------------------------------------
// K1: h = x @ ham via bf16 MFMA (passed R5/R7/R8/R9 — byte-identical).
// ---------------------------------------------------------------------------
__global__ __launch_bounds__(256) void k_h(const unsigned short* __restrict__ xbf,
                                           const unsigned short* __restrict__ hamT,
                                           const float* __restrict__ a,
                                           unsigned short* __restrict__ hBT,
                                           float2* __restrict__ fsE,
                                           float2* __restrict__ fdE) {
    const int t = threadIdx.x;
    const int head = blockIdx.y;
    const int n0 = blockIdx.x * 64;
    const int wv = t >> 6, lane = t & 63;
    const int quad = lane >> 4, nl = lane & 15;
    const unsigned short* ap = xbf + (size_t)(n0 + wv * 16 + nl) * XS + quad * 8;
    const unsigned short* bp = hamT + (size_t)(head * 128 + nl) * XS + quad * 8;
    f32x4 acc[8];
#pragma unroll
    for (int ct = 0; ct < 8; ct++) acc[ct] = (f32x4){0.f, 0.f, 0.f, 0.f};
    for (int kc = 0; kc < 16; kc++) {
        const short8 af = *(const short8*)(ap + kc * 32);
#pragma unroll
        for (int ct = 0; ct < 8; ct++) {
            const short8 bf_ = *(const short8*)(bp + (size_t)ct * 16 * XS + kc * 32);
            acc[ct] = __builtin_amdgcn_mfma_f32_16x16x32_bf16(af, bf_, acc[ct], 0, 0, 0);
        }
    }
    const int rbase = n0 + wv * 16 + quad * 4;
#pragma unroll
    for (int ct = 0; ct < 8; ct++) {
        const uint2 pk = {pack_rne(acc[ct][0], acc[ct][1]), pack_rne(acc[ct][2], acc[ct][3])};
        *(uint2*)(hBT + (size_t)(head * 128 + ct * 16 + nl) * HS + rbase) = pk;
    }
    float fsr[4] = {0.f, 0.f, 0.f, 0.f}, fdr[4] = {0.f, 0.f, 0.f, 0.f};
#pragma unroll
    for (int ct = 0; ct < 8; ct++) {
        const int col = ct * 16 + nl;
        const float as = a[head * 256 + col];
        const float ad = a[head * 256 + 128 + col];
#pragma unroll
        for (int r = 0; r < 4; r++) {
            fsr[r] += acc[ct][r] * as;
            fdr[r] += acc[ct][r] * ad;
        }
    }
#pragma unroll
    for (int off = 1; off < 16; off <<= 1)
#pragma unroll
        for (int r = 0; r < 4; r++) {
            fsr[r] += __shfl_xor(fsr[r], off, 64);
            fdr[r] += __shfl_xor(fdr[r], off, 64);
        }
    if (nl == 0) {
#pragma unroll
        for (int r = 0; r < 4; r++) {
            const int n = rbase + r;
            fsE[(head << 12) + n] = make_float2(__expf(fsr[r]), __expf(ALPHA * fsr[r]));
            fdE[(head << 12) + n] = make_float2(__expf(fdr[r]), __expf(ALPHA * fdr[r]));
        }
    }
}

// ---------------------------------------------------------------------------
// K2 "convoy": h' = softmax(mask(leaky(fs+fd))) @ h, fused ELU.
// Row-split only: block = 64 rows x 128 cols x FULL m; 4 waves own 16 rows
// each and sweep the SAME m-chunks -> B lines fetched once per CU, L1 serves
// the other 3 waves (per-CU fill traffic /4 — the R8/R9 TLP-insensitive wall).
// No m-split => L complete per wave => no LDS, no barriers, trivial epilogue.
// Even/odd register pipeline; compile-time indices only.
// ---------------------------------------------------------------------------
#define WELT(e1, ea, j, bits, es) \
    __uint_as_float(__float_as_uint(fmaxf((es).x * (e1), (es).y * (ea))) & bitmask1((bits), (j)))
#define WPK(f4, jb, bits, es) \
    pack_trunc(WELT((f4).x, (f4).y, (jb), (bits), (es)), \
               WELT((f4).z, (f4).w, (jb) + 1, (bits), (es)))

#define LOADM(S, mcn) do {                                                \
    const int _mo = (mcn) * 32;                                           \
    _Pragma("unroll")                                                     \
    for (int _ct = 0; _ct < 8; _ct++)                                     \
        Bst[S][_ct] = *(const short8*)(bbase + (size_t)_ct * HCS + _mo);  \
    Kst[S] = adjpT[(size_t)(mcn) * 4096 + rowIdx];                        \
    _Pragma("unroll")                                                     \
    for (int _q = 0; _q < 4; _q++) Fst[S][_q] = fdb[(mcn) * 16 + _q];     \
} while (0)

#define EXECM(S) do {                                                     \
    const unsigned int _bits = (Kst[S] >> (quad * 8)) & 0xFFu;            \
    const i32x4 _ai = {(int)WPK(Fst[S][0], 0, _bits, es),                 \
                       (int)WPK(Fst[S][1], 2, _bits, es),                 \
                       (int)WPK(Fst[S][2], 4, _bits, es),                 \
                       (int)WPK(Fst[S][3], 6, _bits, es)};                \
    const short8 _af = __builtin_bit_cast(short8, _ai);                   \
    _Pragma("unroll")                                                     \
    for (int _ct = 0; _ct < 8; _ct++)                                     \
        acc[_ct] = __builtin_amdgcn_mfma_f32_16x16x32_bf16(               \
            _af, Bst[S][_ct], acc[_ct], 0, 0, 0);                         \
    accL = __builtin_amdgcn_mfma_f32_16x16x32_bf16(_af, ones, accL, 0, 0, 0); \
} while (0)

__global__ __launch_bounds__(256, 1) void k_attn(const unsigned int* __restrict__ adjpT,
                                                 const float2* __restrict__ fsE,
                                                 const float2* __restrict__ fdE,
                                                 const unsigned short* __restrict__ hBT,
                                                 float* __restrict__ out) {
    const int t = threadIdx.x;
    const int head = blockIdx.x & 3;           // XCD-pinned head
    const int n0 = (blockIdx.x >> 2) * 64;
    const int wv = t >> 6, lane = t & 63;
    const int quad = lane >> 4, nl = lane & 15;
    const int rowIdx = n0 + wv * 16 + nl;      // this lane's A-row
    const float2 es = fsE[(head << 12) + rowIdx];
    const float4* fdb = (const float4*)(fdE + (head << 12)) + quad * 4;
    const unsigned short* bbase = hBT + (size_t)(head * 128 + nl) * HS + quad * 8;
    const short8 ones = __builtin_bit_cast(short8,
        (i32x4){0x3F803F80, 0x3F803F80, 0x3F803F80, 0x3F803F80});
    f32x4 acc[8];
    f32x4 accL = (f32x4){0.f, 0.f, 0.f, 0.f};
#pragma unroll
    for (int ct = 0; ct < 8; ct++) acc[ct] = (f32x4){0.f, 0.f, 0.f, 0.f};
    short8 Bst[2][8];
    unsigned int Kst[2];
    float4 Fst[2][4];
    LOADM(0, 0);
    LOADM(1, 1);
    for (int mc = 0; mc < 128; mc += 2) {
        EXECM(0);
        LOADM(0, (mc + 2) & 127);              // wrap load harmless
        EXECM(1);
        LOADM(1, (mc + 3) & 127);
    }
    // ---- epilogue: L is complete per wave; normalize + ELU + store ----
    float iLv[4];
#pragma unroll
    for (int r = 0; r < 4; r++) iLv[r] = (accL[r] > 0.f) ? (1.0f / accL[r]) : 0.0f;
#pragma unroll
    for (int ct = 0; ct < 8; ct++)
#pragma unroll
        for (int r = 0; r < 4; r++) {
            float v = acc[ct][r] * iLv[r];
            v = v > 0.f ? v : (__expf(v) - 1.0f);   // ELU(alpha=1)
            out[(size_t)(n0 + wv * 16 + quad * 4 + r) * 512
                + head * 128 + ct * 16 + nl] = v;
        }
}

extern "C" void kernel_launch(void* const* d_in, const int* in_sizes, int n_in,
                              void* d_out, int out_size, void* d_ws, size_t ws_size,
                              hipStream_t stream) {
    (void)in_sizes; (void)n_in; (void)out_size; (void)ws_size;
    const float* x   = (const float*)d_in[0];   // (4096,512) fp32
    const int*   adj = (const int*)d_in[1];     // (4096,4096) i32
    const float* W   = (const float*)d_in[2];   // (4,128,128) fp32
    const float* a   = (const float*)d_in[3];   // (4,256) fp32
    float* out = (float*)d_out;                 // (4096,512) fp32

    char* ws = (char*)d_ws;
    unsigned short* xbf  = (unsigned short*)(ws);             // 4096*544*2 = 4456448
    unsigned short* hBT  = (unsigned short*)(ws + 4456448);   // 4*128*4128*2 = 4227072
    unsigned short* hamT = (unsigned short*)(ws + 8683520);   // 4*128*544*2 = 557056
    unsigned int*   adjpT= (unsigned int*)(ws + 9240576);     // 2 MB bitmask [mc][row]
    float2*         fsE  = (float2*)(ws + 11337728);          // 128 KB
    float2*         fdE  = (float2*)(ws + 11468800);          // 128 KB

    hipLaunchKernelGGL(k_prep, dim3(3200),    dim3(256), 0, stream,
                       x, W, adj, xbf, hamT, adjpT);
    hipLaunchKernelGGL(k_h,    dim3(64, 4),   dim3(256), 0, stream, xbf, hamT, a, hBT, fsE, fdE);
    hipLaunchKernelGGL(k_attn, dim3(256),     dim3(256), 0, stream, adjpT, fsE, fdE, hBT, out);
}